// Round 4
// baseline (143.235 us; speedup 1.0000x reference)
//
#include <hip/hip_runtime.h>
#include <hip/hip_bf16.h>

// SelfAttentionTransformer: B=4, L=2048, D=256, H=8, dk=32, F=1024
// f32 inputs / f32 output. Round 11:
//  - rowsums (softmax denom) extracted from AV GEMM: k_scores shuffle-reduces
//    per-batch masked row partials -> rowpart[row][b][xb]; k_ln1 sums 32 partials
//  - k_av: N=1024 -> grid 256 = exactly 1 block/CU (tail eliminated)
//  - k_gemm2ln: 1Mx4N wave arrangement (LDS reads 72->48 KB/step)
//  - T4 counted-vmcnt pipelines retained everywhere

#define B_ 4
#define L_ 2048
#define D_ 256
#define F_ 1024
#define PI_F 3.14159265358979323846f

typedef __bf16 bf16x8 __attribute__((ext_vector_type(8)));
typedef float floatx4 __attribute__((ext_vector_type(4)));
typedef unsigned short ushortx4 __attribute__((ext_vector_type(4)));

#define WAIT_VM(n) asm volatile("s_waitcnt vmcnt(" #n ")" ::: "memory")
#define SCHED0() __builtin_amdgcn_sched_barrier(0)
#define BARRIER() do { SCHED0(); __builtin_amdgcn_s_barrier(); SCHED0(); } while (0)

__device__ __forceinline__ unsigned short f2bf(float f) {
    unsigned int u = __float_as_uint(f);
    u = (u + 0x7FFFu + ((u >> 16) & 1u)) >> 16;   // RNE
    return (unsigned short)u;
}
__device__ __forceinline__ float bf2f(unsigned short u) {
    union { unsigned int i; float f; } v; v.i = ((unsigned int)u) << 16; return v.f;
}

__device__ __forceinline__ void async_cp16(unsigned short* lds, const unsigned short* g) {
    __builtin_amdgcn_global_load_lds(
        (const __attribute__((address_space(1))) unsigned int*)g,
        (__attribute__((address_space(3))) unsigned int*)lds, 16, 0, 0);
}

// ---------------- prep, compact 1D grid (2816 blocks):
// [0,2048)   x-transpose(masked) -> XmT (1024 rows)
// [2048,2304) W1T transpose
// [2304,2560) W2T transpose
// [2560,2816) mean -> mb bf16
__global__ __launch_bounds__(256) void k_prep(const float* __restrict__ x,
                                              const float* __restrict__ W1,
                                              const float* __restrict__ W2,
                                              const int* __restrict__ mask,
                                              unsigned short* __restrict__ mb,
                                              unsigned short* __restrict__ XmT,
                                              unsigned short* __restrict__ W1T,
                                              unsigned short* __restrict__ W2T) {
    __shared__ float tile[32][33];
    int r = blockIdx.x, t = threadIdx.x;
    if (r >= 2560) {
        int idx = (r - 2560) * 256 + t;   // 0..65535
        int l = idx >> 5, k = idx & 31;
        float s = 0.f;
#pragma unroll
        for (int b = 0; b < B_; b++) {
            const float* xp = x + ((size_t)(b * L_ + l)) * D_ + k;
#pragma unroll
            for (int h = 0; h < 8; h++) s += xp[h * 32];
        }
        mb[idx] = f2bf(s * (1.f / 32.f));
        return;
    }
    const float* in; unsigned short* outp; int R, C; const int* mrow = nullptr; size_t bo = 0;
    int bx, by;
    if (r < 2048) {
        int z = r >> 9, rem = r & 511; by = rem >> 3; bx = rem & 7;
        in = x; outp = XmT; R = L_; C = 256; bo = (size_t)z * R * C; mrow = mask + z * L_;
    } else if (r < 2304) {
        int rem = r - 2048; bx = rem & 31; by = rem >> 5;
        in = W1; outp = W1T; R = 256; C = 1024;
    } else {
        int rem = r - 2304; bx = rem & 7; by = rem >> 3;
        in = W2; outp = W2T; R = 1024; C = 256;
    }
    int r0 = by * 32, c0 = bx * 32;
    int tx = t & 31, ty = t >> 5;
#pragma unroll
    for (int rr = 0; rr < 4; rr++) {
        int rw = ty + rr * 8;
        tile[rw][tx] = in[bo + (size_t)(r0 + rw) * C + c0 + tx];
    }
    float mfac = 1.f;
    if (mrow) mfac = mrow[r0 + tx] ? 1.f : 0.f;
    __syncthreads();
#pragma unroll
    for (int rr = 0; rr < 4; rr++) {
        int c = ty + rr * 8;
        outp[bo + (size_t)(c0 + c) * R + r0 + tx] = f2bf(tile[tx][c] * mfac);
    }
}

// ---------------- E = exp(sin^2(0.5*clip(m.mT))) via MFMA, bf16 out
//                 + per-batch masked row partials -> rowpart[row][b][xb] ----------------
__global__ __launch_bounds__(256) void k_scores_mfma(const unsigned short* __restrict__ mb,
                                                     const int* __restrict__ mask,
                                                     unsigned short* __restrict__ E,
                                                     float* __restrict__ rowpart) {
    __shared__ float part[128][2][4];
    const int t = threadIdx.x, lane = t & 63, wid = t >> 6;
    const int wm = (wid >> 1) * 64, wn = (wid & 1) * 32;
    const int lr = lane & 15, lq = lane >> 4;
    int m0 = blockIdx.y * 128, n0 = blockIdx.x * 64;
    bf16x8 af[4], bfr[2];
#pragma unroll
    for (int i = 0; i < 4; i++)
        af[i] = *(const bf16x8*)(mb + (size_t)(m0 + wm + i * 16 + lr) * 32 + lq * 8);
#pragma unroll
    for (int j = 0; j < 2; j++)
        bfr[j] = *(const bf16x8*)(mb + (size_t)(n0 + wn + j * 16 + lr) * 32 + lq * 8);
    floatx4 acc[4][2];
#pragma unroll
    for (int i = 0; i < 4; i++)
#pragma unroll
        for (int j = 0; j < 2; j++) {
            acc[i][j] = (floatx4){0.f, 0.f, 0.f, 0.f};
            acc[i][j] = __builtin_amdgcn_mfma_f32_16x16x32_bf16(af[i], bfr[j], acc[i][j], 0, 0, 0);
        }
    // mask factors for this lane's two columns
    float mv[4][2];
#pragma unroll
    for (int b = 0; b < 4; b++) {
        mv[b][0] = mask[b * L_ + n0 + wn + lr] ? 1.f : 0.f;
        mv[b][1] = mask[b * L_ + n0 + wn + 16 + lr] ? 1.f : 0.f;
    }
#pragma unroll
    for (int i = 0; i < 4; i++) {
#pragma unroll
        for (int j = 0; j < 2; j++)
#pragma unroll
            for (int r = 0; r < 4; r++) {
                int row = m0 + wm + i * 16 + lq * 4 + r;
                int col = n0 + wn + j * 16 + lr;
                float d = fminf(fmaxf(acc[i][j][r], -PI_F), PI_F);
                float sn = __sinf(0.5f * d);
                float e = __expf(sn * sn);
                acc[i][j][r] = e;
                E[(size_t)row * L_ + col] = f2bf(e);
            }
        // per-batch masked row partials: reduce over the wave's 32 cols
#pragma unroll
        for (int r = 0; r < 4; r++) {
            float pb[4];
#pragma unroll
            for (int b = 0; b < 4; b++)
                pb[b] = acc[i][0][r] * mv[b][0] + acc[i][1][r] * mv[b][1];
#pragma unroll
            for (int o = 1; o < 16; o <<= 1)
#pragma unroll
                for (int b = 0; b < 4; b++) pb[b] += __shfl_xor(pb[b], o);
            if (lr == 0) {
                int lrow = wm + i * 16 + lq * 4 + r;
#pragma unroll
                for (int b = 0; b < 4; b++) part[lrow][wid & 1][b] = pb[b];
            }
        }
    }
    __syncthreads();
    if (t < 128) {
        int grow = m0 + t;
#pragma unroll
        for (int b = 0; b < 4; b++)
            rowpart[((size_t)grow * 4 + b) * 32 + blockIdx.x] = part[t][0][b] + part[t][1][b];
    }
}

// ---------------- AV: C[2048,1024] = E @ XmT^T (bf16 out), 3-deep counted-vmcnt ----------------
__global__ __launch_bounds__(256) void k_av(const unsigned short* __restrict__ E,
                                            const unsigned short* __restrict__ XmT,
                                            unsigned short* __restrict__ Cb) {
    // 3 buffers x (128x64 A + 64x64 B) bf16 = 3 x 24 KB = 72 KB
    __shared__ __align__(16) unsigned short sbuf[3][128 * 64 + 64 * 64];
    const int t = threadIdx.x, lane = t & 63, wid = t >> 6;
    const int wm = (wid >> 1) * 64, wn = (wid & 1) * 32;
    const int lr = lane & 15, lq = lane >> 4;
    const int lrow = lane >> 3, lseg = lane & 7;

    // bijective XCD swizzle: 256 = 8 * 32 -> each XCD gets 2 full M-panels
    int bid = blockIdx.x;
    int swz = (bid & 7) * 32 + (bid >> 3);
    int m0 = (swz >> 4) * 128, n0 = (swz & 15) * 64;

    const unsigned short* Ag[4]; int sAoff[4];
#pragma unroll
    for (int q = 0; q < 4; q++) {
        int rl = wid * 32 + q * 8 + lrow;
        Ag[q] = E + (size_t)(m0 + rl) * L_ + ((lseg - rl) & 7) * 8;
        sAoff[q] = (wid * 32 + q * 8) * 64;
    }
    const unsigned short* Bg[2]; int sBoff[2];
#pragma unroll
    for (int q = 0; q < 2; q++) {
        int rl = wid * 16 + q * 8 + lrow;
        Bg[q] = XmT + (size_t)(n0 + rl) * L_ + ((lseg - rl) & 7) * 8;
        sBoff[q] = 8192 + (wid * 16 + q * 8) * 64;   // B region starts at elem 8192
    }
    int arot[4], aroff[4], brot[2], broff[2];
#pragma unroll
    for (int i = 0; i < 4; i++) { int ar = wm + i * 16 + lr; aroff[i] = ar * 64; arot[i] = lq + ar; }
#pragma unroll
    for (int j = 0; j < 2; j++) { int br = wn + j * 16 + lr; broff[j] = 8192 + br * 64; brot[j] = lq + br; }

    floatx4 acc[4][2];
#pragma unroll
    for (int i = 0; i < 4; i++)
#pragma unroll
        for (int j = 0; j < 2; j++) acc[i][j] = (floatx4){0.f, 0.f, 0.f, 0.f};

    auto stage = [&](unsigned short* base, int k0) {
#pragma unroll
        for (int q = 0; q < 4; q++) async_cp16(base + sAoff[q], Ag[q] + k0);
#pragma unroll
        for (int q = 0; q < 2; q++) async_cp16(base + sBoff[q], Bg[q] + k0);
    };
    auto compute = [&](const unsigned short* base) {
#pragma unroll
        for (int s = 0; s < 2; s++) {
            bf16x8 af[4], bfr[2];
#pragma unroll
            for (int i = 0; i < 4; i++)
                af[i] = *(const bf16x8*)(base + aroff[i] + ((s * 4 + arot[i]) & 7) * 8);
#pragma unroll
            for (int j = 0; j < 2; j++)
                bfr[j] = *(const bf16x8*)(base + broff[j] + ((s * 4 + brot[j]) & 7) * 8);
#pragma unroll
            for (int i = 0; i < 4; i++)
#pragma unroll
                for (int j = 0; j < 2; j++)
                    acc[i][j] = __builtin_amdgcn_mfma_f32_16x16x32_bf16(af[i], bfr[j], acc[i][j], 0, 0, 0);
        }
    };

    unsigned short *p0 = sbuf[0], *p1 = sbuf[1], *p2 = sbuf[2];
    stage(p0, 0); stage(p1, 64); stage(p2, 128);
    WAIT_VM(12); BARRIER();
    for (int p = 0; p < 29; ++p) {
        compute(p0);
        BARRIER();
        stage(p0, (p + 3) << 6);
        WAIT_VM(12); BARRIER();
        unsigned short* tmp = p0; p0 = p1; p1 = p2; p2 = tmp;
    }
    compute(p0);                      // step 29
    BARRIER();
    WAIT_VM(6); BARRIER();            // step 30 ready
    compute(p1);                      // step 30
    BARRIER();
    WAIT_VM(0); BARRIER();            // step 31 ready
    compute(p2);                      // step 31

#pragma unroll
    for (int i = 0; i < 4; i++)
#pragma unroll
        for (int j = 0; j < 2; j++)
#pragma unroll
            for (int r = 0; r < 4; r++) {
                int row = m0 + wm + i * 16 + lq * 4 + r;
                int col = n0 + wn + j * 16 + lr;
                Cb[(size_t)row * 1024 + col] = f2bf(acc[i][j][r]);
            }
}

// ---------------- LN1 fused: v = x + C/rs; LN -> h bf16 (wave per token) ----------------
__global__ __launch_bounds__(256) void k_ln1(const float* __restrict__ x, const unsigned short* __restrict__ Cb,
                                             const float* __restrict__ rowpart,
                                             const float* __restrict__ g_, const float* __restrict__ be_,
                                             unsigned short* __restrict__ hb) {
    int t = threadIdx.x, wid = t >> 6, lane = t & 63;
    int tok = (blockIdx.x << 2) + wid;      // 0..8191
    int b = tok >> 11, i = tok & (L_ - 1);
    float rp = rowpart[((size_t)i * 4 + b) * 32 + (lane & 31)];
#pragma unroll
    for (int o = 1; o < 32; o <<= 1) rp += __shfl_xor(rp, o);
    float rs = rp;
    float4 xv = *(const float4*)(x + (size_t)tok * D_ + lane * 4);
    ushortx4 cv = *(const ushortx4*)(Cb + (size_t)i * 1024 + b * 256 + lane * 4);
    float v0 = xv.x + bf2f(cv.x) / rs;
    float v1 = xv.y + bf2f(cv.y) / rs;
    float v2 = xv.z + bf2f(cv.z) / rs;
    float v3 = xv.w + bf2f(cv.w) / rs;
    float s  = v0 + v1 + v2 + v3;
    float s2 = v0 * v0 + v1 * v1 + v2 * v2 + v3 * v3;
#pragma unroll
    for (int o = 1; o < 64; o <<= 1) { s += __shfl_xor(s, o); s2 += __shfl_xor(s2, o); }
    float mu = s * (1.f / 256.f);
    float var = s2 * (1.f / 256.f) - mu * mu;
    float r = rsqrtf(var + 1e-5f);
    float4 gv = *(const float4*)(g_ + lane * 4);
    float4 bv = *(const float4*)(be_ + lane * 4);
    ushortx4 o4;
    o4.x = f2bf((v0 - mu) * r * gv.x + bv.x);
    o4.y = f2bf((v1 - mu) * r * gv.y + bv.y);
    o4.z = f2bf((v2 - mu) * r * gv.z + bv.z);
    o4.w = f2bf((v3 - mu) * r * gv.w + bv.w);
    *(ushortx4*)(hb + (size_t)tok * D_ + lane * 4) = o4;
}

// ---------------- GEMM1: t1 = relu(h @ W1 + b1) bf16; 128x128 tile, 2-deep counted ----------------
__global__ __launch_bounds__(256) void k_gemm1(const unsigned short* __restrict__ hb,
                                               const unsigned short* __restrict__ W1T,
                                               const float* __restrict__ b1, unsigned short* __restrict__ t1) {
    __shared__ __align__(16) unsigned short sbuf[2][128 * 64 + 128 * 64];  // 2 x 32 KB
    const int t = threadIdx.x, lane = t & 63, wid = t >> 6;
    const int wm = (wid >> 1) * 64, wn = (wid & 1) * 64;
    const int lr = lane & 15, lq = lane >> 4;
    const int lrow8 = lane >> 3, lseg = lane & 7;

    // bijective XCD swizzle: 512 = 8 * 64
    int bid = blockIdx.x;
    int swz = (bid & 7) * 64 + (bid >> 3);
    int m0 = (swz >> 3) * 128, n0 = (swz & 7) * 128;

    const unsigned short* Ag[4]; const unsigned short* Bg[4]; int aoff[4], boff4[4];
#pragma unroll
    for (int q = 0; q < 4; q++) {
        int rl = q * 32 + wid * 8 + lrow8;
        int seg = (lseg - rl) & 7;
        Ag[q] = hb + (size_t)(m0 + rl) * 256 + seg * 8;
        Bg[q] = W1T + (size_t)(n0 + rl) * 256 + seg * 8;
        aoff[q] = (q * 32 + wid * 8) * 64;
        boff4[q] = 8192 + (q * 32 + wid * 8) * 64;
    }
    int arot[4], aroff[4], brot[4], broff[4];
#pragma unroll
    for (int i = 0; i < 4; i++) { int ar = wm + i * 16 + lr; aroff[i] = ar * 64; arot[i] = lq + ar; }
#pragma unroll
    for (int j = 0; j < 4; j++) { int br = wn + j * 16 + lr; broff[j] = 8192 + br * 64; brot[j] = lq + br; }

    floatx4 acc[4][4];
#pragma unroll
    for (int i = 0; i < 4; i++)
#pragma unroll
        for (int j = 0; j < 4; j++) acc[i][j] = (floatx4){0.f, 0.f, 0.f, 0.f};

    auto stage = [&](unsigned short* base, int k0) {
#pragma unroll
        for (int q = 0; q < 4; q++) { async_cp16(base + aoff[q], Ag[q] + k0); async_cp16(base + boff4[q], Bg[q] + k0); }
    };
    auto compute = [&](const unsigned short* base) {
#pragma unroll
        for (int s = 0; s < 2; s++) {
            bf16x8 af[4], bfr[4];
#pragma unroll
            for (int i = 0; i < 4; i++) af[i] = *(const bf16x8*)(base + aroff[i] + ((s * 4 + arot[i]) & 7) * 8);
#pragma unroll
            for (int j = 0; j < 4; j++) bfr[j] = *(const bf16x8*)(base + broff[j] + ((s * 4 + brot[j]) & 7) * 8);
#pragma unroll
            for (int i = 0; i < 4; i++)
#pragma unroll
                for (int j = 0; j < 4; j++)
                    acc[i][j] = __builtin_amdgcn_mfma_f32_16x16x32_bf16(af[i], bfr[j], acc[i][j], 0, 0, 0);
        }
    };

    unsigned short *pa = sbuf[0], *pb = sbuf[1];
    stage(pa, 0); stage(pb, 64);
    WAIT_VM(8); BARRIER();            // step0 ready, step1 (8) in flight
    compute(pa);                      // step0
    BARRIER();
    stage(pa, 128);
    WAIT_VM(8); BARRIER();            // step1 ready, step2 (8) in flight
    compute(pb);                      // step1
    BARRIER();
    stage(pb, 192);
    WAIT_VM(8); BARRIER();            // step2 ready, step3 (8) in flight
    compute(pa);                      // step2
    BARRIER();
    WAIT_VM(0); BARRIER();            // step3 ready
    compute(pb);                      // step3

    float bb[4];
#pragma unroll
    for (int j = 0; j < 4; j++) bb[j] = b1[n0 + wn + j * 16 + lr];
#pragma unroll
    for (int i = 0; i < 4; i++)
#pragma unroll
        for (int j = 0; j < 4; j++) {
            int col = n0 + wn + j * 16 + lr;
#pragma unroll
            for (int r = 0; r < 4; r++) {
                int row = m0 + wm + i * 16 + lq * 4 + r;
                t1[(size_t)row * 1024 + col] = f2bf(fmaxf(acc[i][j][r] + bb[j], 0.f));
            }
        }
}

// ---------------- GEMM2+LN2 fused: out = LN(h + t1 @ W2 + b2), 32x256 tile,
//                  1Mx4N waves (LDS reads -33%), 3-deep counted ----------------
__global__ __launch_bounds__(256) void k_gemm2ln(const unsigned short* __restrict__ t1,
                                                 const unsigned short* __restrict__ W2T,
                                                 const float* __restrict__ b2,
                                                 const unsigned short* __restrict__ hb,
                                                 const float* __restrict__ g_, const float* __restrict__ be_,
                                                 float* __restrict__ out) {
    // 3 buffers x (32x64 A + 256x64 B) bf16 = 3 x 36 KB = 108 KB
    __shared__ __align__(16) unsigned short sbuf[3][32 * 64 + 256 * 64];
    __shared__ float red[4][32][2];
    const int t = threadIdx.x, lane = t & 63, wid = t >> 6;
    const int wn = wid * 64;                 // each wave: all 32 rows x 64-col slice
    const int lr = lane & 15, lq = lane >> 4;
    const int lrow8 = lane >> 3, lseg = lane & 7;
    int m0 = blockIdx.x * 32;

    int arl = wid * 8 + lrow8;
    const unsigned short* Ag = t1 + (size_t)(m0 + arl) * 1024 + (((lseg - arl) & 7) * 8);
    int sAoff = (wid * 8) * 64;
    const unsigned short* Bg[8]; int sBoff[8];
#pragma unroll
    for (int q = 0; q < 8; q++) {
        int rl = q * 32 + wid * 8 + lrow8;
        Bg[q] = W2T + (size_t)rl * 1024 + (((lseg - rl) & 7) * 8);
        sBoff[q] = 2048 + (q * 32 + wid * 8) * 64;    // B region starts at elem 2048
    }
    int aroff[2], arot[2];
#pragma unroll
    for (int i = 0; i < 2; i++) { int ar = i * 16 + lr; aroff[i] = ar * 64; arot[i] = lq + ar; }
    int brot[4], broff[4];
#pragma unroll
    for (int j = 0; j < 4; j++) { int br = wn + j * 16 + lr; broff[j] = 2048 + br * 64; brot[j] = lq + br; }

    floatx4 acc[2][4];
#pragma unroll
    for (int i = 0; i < 2; i++)
#pragma unroll
        for (int j = 0; j < 4; j++) acc[i][j] = (floatx4){0.f, 0.f, 0.f, 0.f};

    auto stage = [&](unsigned short* base, int k0) {
        async_cp16(base + sAoff, Ag + k0);
#pragma unroll
        for (int q = 0; q < 8; q++) async_cp16(base + sBoff[q], Bg[q] + k0);
    };
    auto compute = [&](const unsigned short* base) {
#pragma unroll
        for (int s = 0; s < 2; s++) {
            bf16x8 af[2];
#pragma unroll
            for (int i = 0; i < 2; i++)
                af[i] = *(const bf16x8*)(base + aroff[i] + ((s * 4 + arot[i]) & 7) * 8);
#pragma unroll
            for (int j = 0; j < 4; j++) {
                bf16x8 bfr = *(const bf16x8*)(base + broff[j] + ((s * 4 + brot[j]) & 7) * 8);
#pragma unroll
                for (int i = 0; i < 2; i++)
                    acc[i][j] = __builtin_amdgcn_mfma_f32_16x16x32_bf16(af[i], bfr, acc[i][j], 0, 0, 0);
            }
        }
    };

    unsigned short *p0 = sbuf[0], *p1 = sbuf[1], *p2 = sbuf[2];
    stage(p0, 0); stage(p1, 64); stage(p2, 128);
    WAIT_VM(18); BARRIER();
    for (int p = 0; p < 13; ++p) {
        compute(p0);
        BARRIER();
        stage(p0, (p + 3) << 6);
        WAIT_VM(18); BARRIER();
        unsigned short* tmp = p0; p0 = p1; p1 = p2; p2 = tmp;
    }
    compute(p0);                      // step 13
    BARRIER();
    WAIT_VM(9); BARRIER();            // step 14 ready
    compute(p1);                      // step 14
    BARRIER();
    WAIT_VM(0); BARRIER();            // step 15 ready
    compute(p2);                      // step 15

    float psum[2][4], psq[2][4];
#pragma unroll
    for (int i = 0; i < 2; i++)
#pragma unroll
        for (int r = 0; r < 4; r++) { psum[i][r] = 0.f; psq[i][r] = 0.f; }
#pragma unroll
    for (int i = 0; i < 2; i++)
#pragma unroll
        for (int j = 0; j < 4; j++) {
            int col = wn + j * 16 + lr;
            float bv = b2[col];
#pragma unroll
            for (int r = 0; r < 4; r++) {
                int row = m0 + i * 16 + lq * 4 + r;
                float v = acc[i][j][r] + bv + bf2f(hb[(size_t)row * 256 + col]);
                acc[i][j][r] = v;
                psum[i][r] += v; psq[i][r] += v * v;
            }
        }
#pragma unroll
    for (int o = 1; o < 16; o <<= 1)
#pragma unroll
        for (int i = 0; i < 2; i++)
#pragma unroll
            for (int r = 0; r < 4; r++) { psum[i][r] += __shfl_xor(psum[i][r], o); psq[i][r] += __shfl_xor(psq[i][r], o); }
    if (lr == 0) {
#pragma unroll
        for (int i = 0; i < 2; i++)
#pragma unroll
            for (int r = 0; r < 4; r++) {
                int lrow = i * 16 + lq * 4 + r;
                red[wid][lrow][0] = psum[i][r];
                red[wid][lrow][1] = psq[i][r];
            }
    }
    __syncthreads();
#pragma unroll
    for (int i = 0; i < 2; i++)
#pragma unroll
        for (int r = 0; r < 4; r++) {
            int lrow = i * 16 + lq * 4 + r;
            float s  = red[0][lrow][0] + red[1][lrow][0] + red[2][lrow][0] + red[3][lrow][0];
            float s2 = red[0][lrow][1] + red[1][lrow][1] + red[2][lrow][1] + red[3][lrow][1];
            float mu = s * (1.f / 256.f);
            float var = s2 * (1.f / 256.f) - mu * mu;
            float rc = rsqrtf(var + 1e-5f);
            int row = m0 + lrow;
#pragma unroll
            for (int j = 0; j < 4; j++) {
                int col = wn + j * 16 + lr;
                out[(size_t)row * 256 + col] = (acc[i][j][r] - mu) * rc * g_[col] + be_[col];
            }
        }
}

extern "C" void kernel_launch(void* const* d_in, const int* in_sizes, int n_in,
                              void* d_out, int out_size, void* d_ws, size_t ws_size,
                              hipStream_t stream) {
    const float* x   = (const float*)d_in[0];
    const int*  mask = (const int*)d_in[1];
    const float* W1  = (const float*)d_in[2];
    const float* b1  = (const float*)d_in[3];
    const float* W2  = (const float*)d_in[4];
    const float* b2  = (const float*)d_in[5];
    const float* g1  = (const float*)d_in[6];
    const float* be1 = (const float*)d_in[7];
    const float* g2  = (const float*)d_in[8];
    const float* be2 = (const float*)d_in[9];
    float* out = (float*)d_out;

    char* w = (char*)d_ws;
    unsigned short* mb_   = (unsigned short*)w;  w += 65536 * 2;                 // 128 KB
    unsigned short* E_    = (unsigned short*)w;  w += (size_t)L_ * L_ * 2;       // 8 MB
    unsigned short* XmT_  = (unsigned short*)w;  w += (size_t)1024 * L_ * 2;     // 4 MB
    unsigned short* W1T_  = (unsigned short*)w;  w += 262144 * 2;                // 512 KB
    unsigned short* W2T_  = (unsigned short*)w;  w += 262144 * 2;                // 512 KB
    unsigned short* Cb_   = (unsigned short*)w;  w += (size_t)L_ * 1024 * 2;     // 4 MB
    unsigned short* hb_   = (unsigned short*)w;  w += (size_t)8192 * 256 * 2;    // 4 MB
    unsigned short* t1_   = (unsigned short*)w;  w += (size_t)8192 * 1024 * 2;   // 16 MB
    float*          rp_   = (float*)w;           w += (size_t)2048 * 4 * 32 * 4; // 1 MB

    k_prep<<<2816, 256, 0, stream>>>(x, W1, W2, mask, mb_, XmT_, W1T_, W2T_);
    k_scores_mfma<<<dim3(32, 16), 256, 0, stream>>>(mb_, mask, E_, rp_);
    k_av<<<256, 256, 0, stream>>>(E_, XmT_, Cb_);
    k_ln1<<<2048, 256, 0, stream>>>(x, Cb_, rp_, g1, be1, hb_);
    k_gemm1<<<512, 256, 0, stream>>>(hb_, W1T_, b1, t1_);
    k_gemm2ln<<<256, 256, 0, stream>>>(t1_, W2T_, b2, hb_, g2, be2, out);
}

// Round 5
// 137.534 us; speedup vs baseline: 1.0414x; 1.0414x over previous
//
#include <hip/hip_runtime.h>
#include <hip/hip_bf16.h>

// SelfAttentionTransformer: B=4, L=2048, D=256, H=8, dk=32, F=1024
// f32 inputs / f32 output. Round 12 (= Round 10 base + gemm2ln 1Mx4N rewire;
// rowpart machinery of Round 11 reverted -- it cost more than it saved):
//  - T4 counted-vmcnt pipelines everywhere (raw s_barrier, never vmcnt(0) mid-loop)
//  - k_av: N=1088 (rowsum folded as mask cols), 3-deep, 72 KB LDS (2 blocks/CU)
//  - k_gemm2ln: 1Mx4N waves (LDS reads 72->48 KB/step), 3-deep
//  - k_gemm1: 2-deep unrolled; k_ln1 wave-per-token vectorized

#define B_ 4
#define L_ 2048
#define D_ 256
#define F_ 1024
#define PI_F 3.14159265358979323846f

typedef __bf16 bf16x8 __attribute__((ext_vector_type(8)));
typedef float floatx4 __attribute__((ext_vector_type(4)));
typedef unsigned short ushortx4 __attribute__((ext_vector_type(4)));

#define WAIT_VM(n) asm volatile("s_waitcnt vmcnt(" #n ")" ::: "memory")
#define SCHED0() __builtin_amdgcn_sched_barrier(0)
#define BARRIER() do { SCHED0(); __builtin_amdgcn_s_barrier(); SCHED0(); } while (0)

__device__ __forceinline__ unsigned short f2bf(float f) {
    unsigned int u = __float_as_uint(f);
    u = (u + 0x7FFFu + ((u >> 16) & 1u)) >> 16;   // RNE
    return (unsigned short)u;
}
__device__ __forceinline__ float bf2f(unsigned short u) {
    union { unsigned int i; float f; } v; v.i = ((unsigned int)u) << 16; return v.f;
}

__device__ __forceinline__ void async_cp16(unsigned short* lds, const unsigned short* g) {
    __builtin_amdgcn_global_load_lds(
        (const __attribute__((address_space(1))) unsigned int*)g,
        (__attribute__((address_space(3))) unsigned int*)lds, 16, 0, 0);
}

// ---------------- prep, compact 1D grid (2817 blocks):
// [0,2048)   x-transpose(masked) -> XmT rows 0..1023
// [2048,2304) W1T transpose
// [2304,2560) W2T transpose
// [2560,2816) mean -> mb bf16
// 2816        mask rows -> XmT rows 1024..1027
__global__ __launch_bounds__(256) void k_prep(const float* __restrict__ x,
                                              const float* __restrict__ W1,
                                              const float* __restrict__ W2,
                                              const int* __restrict__ mask,
                                              unsigned short* __restrict__ mb,
                                              unsigned short* __restrict__ XmT,
                                              unsigned short* __restrict__ W1T,
                                              unsigned short* __restrict__ W2T) {
    __shared__ float tile[32][33];
    int r = blockIdx.x, t = threadIdx.x;
    if (r >= 2560) {
        if (r < 2816) {
            int idx = (r - 2560) * 256 + t;   // 0..65535
            int l = idx >> 5, k = idx & 31;
            float s = 0.f;
#pragma unroll
            for (int b = 0; b < B_; b++) {
                const float* xp = x + ((size_t)(b * L_ + l)) * D_ + k;
#pragma unroll
                for (int h = 0; h < 8; h++) s += xp[h * 32];
            }
            mb[idx] = f2bf(s * (1.f / 32.f));
        } else {
#pragma unroll
            for (int c = 0; c < 32; c++) {
                int e = c * 256 + t;          // 0..8191
                int b = e >> 11, j = e & (L_ - 1);
                XmT[(size_t)(1024 + b) * L_ + j] = mask[b * L_ + j] ? 0x3F80 : 0;
            }
        }
        return;
    }
    const float* in; unsigned short* outp; int R, C; const int* mrow = nullptr; size_t bo = 0;
    int bx, by;
    if (r < 2048) {
        int z = r >> 9, rem = r & 511; by = rem >> 3; bx = rem & 7;
        in = x; outp = XmT; R = L_; C = 256; bo = (size_t)z * R * C; mrow = mask + z * L_;
    } else if (r < 2304) {
        int rem = r - 2048; bx = rem & 31; by = rem >> 5;
        in = W1; outp = W1T; R = 256; C = 1024;
    } else {
        int rem = r - 2304; bx = rem & 7; by = rem >> 3;
        in = W2; outp = W2T; R = 1024; C = 256;
    }
    int r0 = by * 32, c0 = bx * 32;
    int tx = t & 31, ty = t >> 5;
#pragma unroll
    for (int rr = 0; rr < 4; rr++) {
        int rw = ty + rr * 8;
        tile[rw][tx] = in[bo + (size_t)(r0 + rw) * C + c0 + tx];
    }
    float mfac = 1.f;
    if (mrow) mfac = mrow[r0 + tx] ? 1.f : 0.f;
    __syncthreads();
#pragma unroll
    for (int rr = 0; rr < 4; rr++) {
        int c = ty + rr * 8;
        outp[bo + (size_t)(c0 + c) * R + r0 + tx] = f2bf(tile[tx][c] * mfac);
    }
}

// ---------------- E = exp(sin^2(0.5*clip(m.mT))) via MFMA, bf16 out ----------------
__global__ __launch_bounds__(256) void k_scores_mfma(const unsigned short* __restrict__ mb,
                                                     unsigned short* __restrict__ E) {
    const int t = threadIdx.x, lane = t & 63, wid = t >> 6;
    const int wm = (wid >> 1) * 64, wn = (wid & 1) * 32;
    const int lr = lane & 15, lq = lane >> 4;
    int m0 = blockIdx.y * 128, n0 = blockIdx.x * 64;
    bf16x8 af[4], bfr[2];
#pragma unroll
    for (int i = 0; i < 4; i++)
        af[i] = *(const bf16x8*)(mb + (size_t)(m0 + wm + i * 16 + lr) * 32 + lq * 8);
#pragma unroll
    for (int j = 0; j < 2; j++)
        bfr[j] = *(const bf16x8*)(mb + (size_t)(n0 + wn + j * 16 + lr) * 32 + lq * 8);
    floatx4 acc[4][2];
#pragma unroll
    for (int i = 0; i < 4; i++)
#pragma unroll
        for (int j = 0; j < 2; j++) {
            acc[i][j] = (floatx4){0.f, 0.f, 0.f, 0.f};
            acc[i][j] = __builtin_amdgcn_mfma_f32_16x16x32_bf16(af[i], bfr[j], acc[i][j], 0, 0, 0);
        }
#pragma unroll
    for (int i = 0; i < 4; i++)
#pragma unroll
        for (int j = 0; j < 2; j++)
#pragma unroll
            for (int r = 0; r < 4; r++) {
                int row = m0 + wm + i * 16 + lq * 4 + r;
                int col = n0 + wn + j * 16 + lr;
                float d = fminf(fmaxf(acc[i][j][r], -PI_F), PI_F);
                float sn = __sinf(0.5f * d);
                E[(size_t)row * L_ + col] = f2bf(__expf(sn * sn));
            }
}

// ---------------- AV: C[2048,1088] = E @ XmT^T (bf16 out), 3-deep counted-vmcnt ----------------
__global__ __launch_bounds__(256) void k_av(const unsigned short* __restrict__ E,
                                            const unsigned short* __restrict__ XmT,
                                            unsigned short* __restrict__ Cb) {
    // 3 buffers x (128x64 A + 64x64 B) bf16 = 3 x 24 KB = 72 KB -> 2 blocks/CU
    __shared__ __align__(16) unsigned short sbuf[3][128 * 64 + 64 * 64];
    const int t = threadIdx.x, lane = t & 63, wid = t >> 6;
    const int wm = (wid >> 1) * 64, wn = (wid & 1) * 32;
    const int lr = lane & 15, lq = lane >> 4;
    const int lrow = lane >> 3, lseg = lane & 7;

    // bijective XCD swizzle: 272 = 8 * 34
    int bid = blockIdx.x;
    int swz = (bid & 7) * 34 + (bid >> 3);
    int m0 = (swz / 17) * 128, n0 = (swz % 17) * 64;

    const unsigned short* Ag[4]; int sAoff[4];
#pragma unroll
    for (int q = 0; q < 4; q++) {
        int rl = wid * 32 + q * 8 + lrow;
        Ag[q] = E + (size_t)(m0 + rl) * L_ + ((lseg - rl) & 7) * 8;
        sAoff[q] = (wid * 32 + q * 8) * 64;
    }
    const unsigned short* Bg[2]; int sBoff[2];
#pragma unroll
    for (int q = 0; q < 2; q++) {
        int rl = wid * 16 + q * 8 + lrow;
        Bg[q] = XmT + (size_t)(n0 + rl) * L_ + ((lseg - rl) & 7) * 8;
        sBoff[q] = 8192 + (wid * 16 + q * 8) * 64;   // B region starts at elem 8192
    }
    int arot[4], aroff[4], brot[2], broff[2];
#pragma unroll
    for (int i = 0; i < 4; i++) { int ar = wm + i * 16 + lr; aroff[i] = ar * 64; arot[i] = lq + ar; }
#pragma unroll
    for (int j = 0; j < 2; j++) { int br = wn + j * 16 + lr; broff[j] = 8192 + br * 64; brot[j] = lq + br; }

    floatx4 acc[4][2];
#pragma unroll
    for (int i = 0; i < 4; i++)
#pragma unroll
        for (int j = 0; j < 2; j++) acc[i][j] = (floatx4){0.f, 0.f, 0.f, 0.f};

    auto stage = [&](unsigned short* base, int k0) {
#pragma unroll
        for (int q = 0; q < 4; q++) async_cp16(base + sAoff[q], Ag[q] + k0);
#pragma unroll
        for (int q = 0; q < 2; q++) async_cp16(base + sBoff[q], Bg[q] + k0);
    };
    auto compute = [&](const unsigned short* base) {
#pragma unroll
        for (int s = 0; s < 2; s++) {
            bf16x8 af[4], bfr[2];
#pragma unroll
            for (int i = 0; i < 4; i++)
                af[i] = *(const bf16x8*)(base + aroff[i] + ((s * 4 + arot[i]) & 7) * 8);
#pragma unroll
            for (int j = 0; j < 2; j++)
                bfr[j] = *(const bf16x8*)(base + broff[j] + ((s * 4 + brot[j]) & 7) * 8);
#pragma unroll
            for (int i = 0; i < 4; i++)
#pragma unroll
                for (int j = 0; j < 2; j++)
                    acc[i][j] = __builtin_amdgcn_mfma_f32_16x16x32_bf16(af[i], bfr[j], acc[i][j], 0, 0, 0);
        }
    };

    unsigned short *p0 = sbuf[0], *p1 = sbuf[1], *p2 = sbuf[2];
    stage(p0, 0); stage(p1, 64); stage(p2, 128);
    WAIT_VM(12); BARRIER();
    for (int p = 0; p < 29; ++p) {
        compute(p0);
        BARRIER();
        stage(p0, (p + 3) << 6);
        WAIT_VM(12); BARRIER();
        unsigned short* tmp = p0; p0 = p1; p1 = p2; p2 = tmp;
    }
    compute(p0);                      // step 29
    BARRIER();
    WAIT_VM(6); BARRIER();            // step 30 ready
    compute(p1);                      // step 30
    BARRIER();
    WAIT_VM(0); BARRIER();            // step 31 ready
    compute(p2);                      // step 31

#pragma unroll
    for (int i = 0; i < 4; i++)
#pragma unroll
        for (int j = 0; j < 2; j++)
#pragma unroll
            for (int r = 0; r < 4; r++) {
                int row = m0 + wm + i * 16 + lq * 4 + r;
                int col = n0 + wn + j * 16 + lr;
                Cb[(size_t)row * 1088 + col] = f2bf(acc[i][j][r]);
            }
}

// ---------------- LN1 fused: v = x + C/rs; LN -> h bf16 (wave per token) ----------------
__global__ __launch_bounds__(256) void k_ln1(const float* __restrict__ x, const unsigned short* __restrict__ Cb,
                                             const float* __restrict__ g_, const float* __restrict__ be_,
                                             unsigned short* __restrict__ hb) {
    int t = threadIdx.x, wid = t >> 6, lane = t & 63;
    int tok = (blockIdx.x << 2) + wid;      // 0..8191
    int b = tok >> 11, i = tok & (L_ - 1);
    float rs = bf2f(Cb[(size_t)i * 1088 + 1024 + b]);
    float4 xv = *(const float4*)(x + (size_t)tok * D_ + lane * 4);
    ushortx4 cv = *(const ushortx4*)(Cb + (size_t)i * 1088 + b * 256 + lane * 4);
    float v0 = xv.x + bf2f(cv.x) / rs;
    float v1 = xv.y + bf2f(cv.y) / rs;
    float v2 = xv.z + bf2f(cv.z) / rs;
    float v3 = xv.w + bf2f(cv.w) / rs;
    float s  = v0 + v1 + v2 + v3;
    float s2 = v0 * v0 + v1 * v1 + v2 * v2 + v3 * v3;
#pragma unroll
    for (int o = 1; o < 64; o <<= 1) { s += __shfl_xor(s, o); s2 += __shfl_xor(s2, o); }
    float mu = s * (1.f / 256.f);
    float var = s2 * (1.f / 256.f) - mu * mu;
    float r = rsqrtf(var + 1e-5f);
    float4 gv = *(const float4*)(g_ + lane * 4);
    float4 bv = *(const float4*)(be_ + lane * 4);
    ushortx4 o4;
    o4.x = f2bf((v0 - mu) * r * gv.x + bv.x);
    o4.y = f2bf((v1 - mu) * r * gv.y + bv.y);
    o4.z = f2bf((v2 - mu) * r * gv.z + bv.z);
    o4.w = f2bf((v3 - mu) * r * gv.w + bv.w);
    *(ushortx4*)(hb + (size_t)tok * D_ + lane * 4) = o4;
}

// ---------------- GEMM1: t1 = relu(h @ W1 + b1) bf16; 128x128 tile, 2-deep counted ----------------
__global__ __launch_bounds__(256) void k_gemm1(const unsigned short* __restrict__ hb,
                                               const unsigned short* __restrict__ W1T,
                                               const float* __restrict__ b1, unsigned short* __restrict__ t1) {
    __shared__ __align__(16) unsigned short sbuf[2][128 * 64 + 128 * 64];  // 2 x 32 KB
    const int t = threadIdx.x, lane = t & 63, wid = t >> 6;
    const int wm = (wid >> 1) * 64, wn = (wid & 1) * 64;
    const int lr = lane & 15, lq = lane >> 4;
    const int lrow8 = lane >> 3, lseg = lane & 7;

    // bijective XCD swizzle: 512 = 8 * 64
    int bid = blockIdx.x;
    int swz = (bid & 7) * 64 + (bid >> 3);
    int m0 = (swz >> 3) * 128, n0 = (swz & 7) * 128;

    const unsigned short* Ag[4]; const unsigned short* Bg[4]; int aoff[4], boff4[4];
#pragma unroll
    for (int q = 0; q < 4; q++) {
        int rl = q * 32 + wid * 8 + lrow8;
        int seg = (lseg - rl) & 7;
        Ag[q] = hb + (size_t)(m0 + rl) * 256 + seg * 8;
        Bg[q] = W1T + (size_t)(n0 + rl) * 256 + seg * 8;
        aoff[q] = (q * 32 + wid * 8) * 64;
        boff4[q] = 8192 + (q * 32 + wid * 8) * 64;
    }
    int arot[4], aroff[4], brot[4], broff[4];
#pragma unroll
    for (int i = 0; i < 4; i++) { int ar = wm + i * 16 + lr; aroff[i] = ar * 64; arot[i] = lq + ar; }
#pragma unroll
    for (int j = 0; j < 4; j++) { int br = wn + j * 16 + lr; broff[j] = 8192 + br * 64; brot[j] = lq + br; }

    floatx4 acc[4][4];
#pragma unroll
    for (int i = 0; i < 4; i++)
#pragma unroll
        for (int j = 0; j < 4; j++) acc[i][j] = (floatx4){0.f, 0.f, 0.f, 0.f};

    auto stage = [&](unsigned short* base, int k0) {
#pragma unroll
        for (int q = 0; q < 4; q++) { async_cp16(base + aoff[q], Ag[q] + k0); async_cp16(base + boff4[q], Bg[q] + k0); }
    };
    auto compute = [&](const unsigned short* base) {
#pragma unroll
        for (int s = 0; s < 2; s++) {
            bf16x8 af[4], bfr[4];
#pragma unroll
            for (int i = 0; i < 4; i++) af[i] = *(const bf16x8*)(base + aroff[i] + ((s * 4 + arot[i]) & 7) * 8);
#pragma unroll
            for (int j = 0; j < 4; j++) bfr[j] = *(const bf16x8*)(base + broff[j] + ((s * 4 + brot[j]) & 7) * 8);
#pragma unroll
            for (int i = 0; i < 4; i++)
#pragma unroll
                for (int j = 0; j < 4; j++)
                    acc[i][j] = __builtin_amdgcn_mfma_f32_16x16x32_bf16(af[i], bfr[j], acc[i][j], 0, 0, 0);
        }
    };

    unsigned short *pa = sbuf[0], *pb = sbuf[1];
    stage(pa, 0); stage(pb, 64);
    WAIT_VM(8); BARRIER();            // step0 ready, step1 (8) in flight
    compute(pa);                      // step0
    BARRIER();
    stage(pa, 128);
    WAIT_VM(8); BARRIER();            // step1 ready, step2 (8) in flight
    compute(pb);                      // step1
    BARRIER();
    stage(pb, 192);
    WAIT_VM(8); BARRIER();            // step2 ready, step3 (8) in flight
    compute(pa);                      // step2
    BARRIER();
    WAIT_VM(0); BARRIER();            // step3 ready
    compute(pb);                      // step3

    float bb[4];
#pragma unroll
    for (int j = 0; j < 4; j++) bb[j] = b1[n0 + wn + j * 16 + lr];
#pragma unroll
    for (int i = 0; i < 4; i++)
#pragma unroll
        for (int j = 0; j < 4; j++) {
            int col = n0 + wn + j * 16 + lr;
#pragma unroll
            for (int r = 0; r < 4; r++) {
                int row = m0 + wm + i * 16 + lq * 4 + r;
                t1[(size_t)row * 1024 + col] = f2bf(fmaxf(acc[i][j][r] + bb[j], 0.f));
            }
        }
}

// ---------------- GEMM2+LN2 fused: out = LN(h + t1 @ W2 + b2), 32x256 tile,
//                  1Mx4N waves (LDS reads -33%), 3-deep counted ----------------
__global__ __launch_bounds__(256) void k_gemm2ln(const unsigned short* __restrict__ t1,
                                                 const unsigned short* __restrict__ W2T,
                                                 const float* __restrict__ b2,
                                                 const unsigned short* __restrict__ hb,
                                                 const float* __restrict__ g_, const float* __restrict__ be_,
                                                 float* __restrict__ out) {
    // 3 buffers x (32x64 A + 256x64 B) bf16 = 3 x 36 KB = 108 KB
    __shared__ __align__(16) unsigned short sbuf[3][32 * 64 + 256 * 64];
    __shared__ float red[4][32][2];
    const int t = threadIdx.x, lane = t & 63, wid = t >> 6;
    const int wn = wid * 64;                 // each wave: all 32 rows x 64-col slice
    const int lr = lane & 15, lq = lane >> 4;
    const int lrow8 = lane >> 3, lseg = lane & 7;
    int m0 = blockIdx.x * 32;

    int arl = wid * 8 + lrow8;
    const unsigned short* Ag = t1 + (size_t)(m0 + arl) * 1024 + (((lseg - arl) & 7) * 8);
    int sAoff = (wid * 8) * 64;
    const unsigned short* Bg[8]; int sBoff[8];
#pragma unroll
    for (int q = 0; q < 8; q++) {
        int rl = q * 32 + wid * 8 + lrow8;
        Bg[q] = W2T + (size_t)rl * 1024 + (((lseg - rl) & 7) * 8);
        sBoff[q] = 2048 + (q * 32 + wid * 8) * 64;    // B region starts at elem 2048
    }
    int aroff[2], arot[2];
#pragma unroll
    for (int i = 0; i < 2; i++) { int ar = i * 16 + lr; aroff[i] = ar * 64; arot[i] = lq + ar; }
    int brot[4], broff[4];
#pragma unroll
    for (int j = 0; j < 4; j++) { int br = wn + j * 16 + lr; broff[j] = 2048 + br * 64; brot[j] = lq + br; }

    floatx4 acc[2][4];
#pragma unroll
    for (int i = 0; i < 2; i++)
#pragma unroll
        for (int j = 0; j < 4; j++) acc[i][j] = (floatx4){0.f, 0.f, 0.f, 0.f};

    auto stage = [&](unsigned short* base, int k0) {
        async_cp16(base + sAoff, Ag + k0);
#pragma unroll
        for (int q = 0; q < 8; q++) async_cp16(base + sBoff[q], Bg[q] + k0);
    };
    auto compute = [&](const unsigned short* base) {
#pragma unroll
        for (int s = 0; s < 2; s++) {
            bf16x8 af[2];
#pragma unroll
            for (int i = 0; i < 2; i++)
                af[i] = *(const bf16x8*)(base + aroff[i] + ((s * 4 + arot[i]) & 7) * 8);
#pragma unroll
            for (int j = 0; j < 4; j++) {
                bf16x8 bfr = *(const bf16x8*)(base + broff[j] + ((s * 4 + brot[j]) & 7) * 8);
#pragma unroll
                for (int i = 0; i < 2; i++)
                    acc[i][j] = __builtin_amdgcn_mfma_f32_16x16x32_bf16(af[i], bfr, acc[i][j], 0, 0, 0);
            }
        }
    };

    unsigned short *p0 = sbuf[0], *p1 = sbuf[1], *p2 = sbuf[2];
    stage(p0, 0); stage(p1, 64); stage(p2, 128);
    WAIT_VM(18); BARRIER();
    for (int p = 0; p < 13; ++p) {
        compute(p0);
        BARRIER();
        stage(p0, (p + 3) << 6);
        WAIT_VM(18); BARRIER();
        unsigned short* tmp = p0; p0 = p1; p1 = p2; p2 = tmp;
    }
    compute(p0);                      // step 13
    BARRIER();
    WAIT_VM(9); BARRIER();            // step 14 ready
    compute(p1);                      // step 14
    BARRIER();
    WAIT_VM(0); BARRIER();            // step 15 ready
    compute(p2);                      // step 15

    float psum[2][4], psq[2][4];
#pragma unroll
    for (int i = 0; i < 2; i++)
#pragma unroll
        for (int r = 0; r < 4; r++) { psum[i][r] = 0.f; psq[i][r] = 0.f; }
#pragma unroll
    for (int i = 0; i < 2; i++)
#pragma unroll
        for (int j = 0; j < 4; j++) {
            int col = wn + j * 16 + lr;
            float bv = b2[col];
#pragma unroll
            for (int r = 0; r < 4; r++) {
                int row = m0 + i * 16 + lq * 4 + r;
                float v = acc[i][j][r] + bv + bf2f(hb[(size_t)row * 256 + col]);
                acc[i][j][r] = v;
                psum[i][r] += v; psq[i][r] += v * v;
            }
        }
#pragma unroll
    for (int o = 1; o < 16; o <<= 1)
#pragma unroll
        for (int i = 0; i < 2; i++)
#pragma unroll
            for (int r = 0; r < 4; r++) { psum[i][r] += __shfl_xor(psum[i][r], o); psq[i][r] += __shfl_xor(psq[i][r], o); }
    if (lr == 0) {
#pragma unroll
        for (int i = 0; i < 2; i++)
#pragma unroll
            for (int r = 0; r < 4; r++) {
                int lrow = i * 16 + lq * 4 + r;
                red[wid][lrow][0] = psum[i][r];
                red[wid][lrow][1] = psq[i][r];
            }
    }
    __syncthreads();
#pragma unroll
    for (int i = 0; i < 2; i++)
#pragma unroll
        for (int r = 0; r < 4; r++) {
            int lrow = i * 16 + lq * 4 + r;
            float s  = red[0][lrow][0] + red[1][lrow][0] + red[2][lrow][0] + red[3][lrow][0];
            float s2 = red[0][lrow][1] + red[1][lrow][1] + red[2][lrow][1] + red[3][lrow][1];
            float mu = s * (1.f / 256.f);
            float var = s2 * (1.f / 256.f) - mu * mu;
            float rc = rsqrtf(var + 1e-5f);
            int row = m0 + lrow;
#pragma unroll
            for (int j = 0; j < 4; j++) {
                int col = wn + j * 16 + lr;
                out[(size_t)row * 256 + col] = (acc[i][j][r] - mu) * rc * g_[col] + be_[col];
            }
        }
}

extern "C" void kernel_launch(void* const* d_in, const int* in_sizes, int n_in,
                              void* d_out, int out_size, void* d_ws, size_t ws_size,
                              hipStream_t stream) {
    const float* x   = (const float*)d_in[0];
    const int*  mask = (const int*)d_in[1];
    const float* W1  = (const float*)d_in[2];
    const float* b1  = (const float*)d_in[3];
    const float* W2  = (const float*)d_in[4];
    const float* b2  = (const float*)d_in[5];
    const float* g1  = (const float*)d_in[6];
    const float* be1 = (const float*)d_in[7];
    const float* g2  = (const float*)d_in[8];
    const float* be2 = (const float*)d_in[9];
    float* out = (float*)d_out;

    char* w = (char*)d_ws;
    unsigned short* mb_   = (unsigned short*)w;  w += 65536 * 2;                 // 128 KB
    unsigned short* E_    = (unsigned short*)w;  w += (size_t)L_ * L_ * 2;       // 8 MB
    unsigned short* XmT_  = (unsigned short*)w;  w += (size_t)1088 * L_ * 2;     // 4.25 MB
    unsigned short* W1T_  = (unsigned short*)w;  w += 262144 * 2;                // 512 KB
    unsigned short* W2T_  = (unsigned short*)w;  w += 262144 * 2;                // 512 KB
    unsigned short* Cb_   = (unsigned short*)w;  w += (size_t)L_ * 1088 * 2;     // 4.25 MB
    unsigned short* hb_   = (unsigned short*)w;  w += (size_t)8192 * 256 * 2;    // 4 MB
    unsigned short* t1_   = (unsigned short*)w;  w += (size_t)8192 * 1024 * 2;   // 16 MB

    k_prep<<<2817, 256, 0, stream>>>(x, W1, W2, mask, mb_, XmT_, W1T_, W2T_);
    k_scores_mfma<<<dim3(32, 16), 256, 0, stream>>>(mb_, E_);
    k_av<<<272, 256, 0, stream>>>(E_, XmT_, Cb_);
    k_ln1<<<2048, 256, 0, stream>>>(x, Cb_, g1, be1, hb_);
    k_gemm1<<<512, 256, 0, stream>>>(hb_, W1T_, b1, t1_);
    k_gemm2ln<<<256, 256, 0, stream>>>(t1_, W2T_, b2, hb_, g2, be2, out);
}

// Round 6
// 133.964 us; speedup vs baseline: 1.0692x; 1.0267x over previous
//
#include <hip/hip_runtime.h>
#include <hip/hip_bf16.h>

// SelfAttentionTransformer: B=4, L=2048, D=256, H=8, dk=32, F=1024
// f32 inputs / f32 output. Round 13:
//  - FFN mega-fusion: k_ln1 + k_gemm1 + k_gemm2ln -> ONE k_ffn (256 blocks x 32 tokens)
//    * h computed in LDS (no hb), t1 kept as per-chunk LDS tile (no 32 MB round-trip)
//    * h A-fragments hoisted to 64 VGPRs (read once, used by all 16 f-chunks)
//    * W1 2-deep LDS dbuf + W2 1-deep staged a chunk ahead, counted vmcnt, raw barriers
//  - k_prep / k_scores / k_av unchanged (validated, R12 = 137.5 us)

#define B_ 4
#define L_ 2048
#define D_ 256
#define F_ 1024
#define PI_F 3.14159265358979323846f

typedef __bf16 bf16x8 __attribute__((ext_vector_type(8)));
typedef float floatx4 __attribute__((ext_vector_type(4)));
typedef unsigned short ushortx4 __attribute__((ext_vector_type(4)));
typedef unsigned short ushortx8 __attribute__((ext_vector_type(8)));

#define WAIT_VM(n) asm volatile("s_waitcnt vmcnt(" #n ")" ::: "memory")
#define WAIT_LGKM() asm volatile("s_waitcnt lgkmcnt(0)" ::: "memory")
#define SCHED0() __builtin_amdgcn_sched_barrier(0)
#define BARRIER() do { SCHED0(); __builtin_amdgcn_s_barrier(); SCHED0(); } while (0)

__device__ __forceinline__ unsigned short f2bf(float f) {
    unsigned int u = __float_as_uint(f);
    u = (u + 0x7FFFu + ((u >> 16) & 1u)) >> 16;   // RNE
    return (unsigned short)u;
}
__device__ __forceinline__ float bf2f(unsigned short u) {
    union { unsigned int i; float f; } v; v.i = ((unsigned int)u) << 16; return v.f;
}

__device__ __forceinline__ void async_cp16(unsigned short* lds, const unsigned short* g) {
    __builtin_amdgcn_global_load_lds(
        (const __attribute__((address_space(1))) unsigned int*)g,
        (__attribute__((address_space(3))) unsigned int*)lds, 16, 0, 0);
}

// ---------------- prep, compact 1D grid (2817 blocks) ----------------
__global__ __launch_bounds__(256) void k_prep(const float* __restrict__ x,
                                              const float* __restrict__ W1,
                                              const float* __restrict__ W2,
                                              const int* __restrict__ mask,
                                              unsigned short* __restrict__ mb,
                                              unsigned short* __restrict__ XmT,
                                              unsigned short* __restrict__ W1T,
                                              unsigned short* __restrict__ W2T) {
    __shared__ float tile[32][33];
    int r = blockIdx.x, t = threadIdx.x;
    if (r >= 2560) {
        if (r < 2816) {
            int idx = (r - 2560) * 256 + t;   // 0..65535
            int l = idx >> 5, k = idx & 31;
            float s = 0.f;
#pragma unroll
            for (int b = 0; b < B_; b++) {
                const float* xp = x + ((size_t)(b * L_ + l)) * D_ + k;
#pragma unroll
                for (int h = 0; h < 8; h++) s += xp[h * 32];
            }
            mb[idx] = f2bf(s * (1.f / 32.f));
        } else {
#pragma unroll
            for (int c = 0; c < 32; c++) {
                int e = c * 256 + t;          // 0..8191
                int b = e >> 11, j = e & (L_ - 1);
                XmT[(size_t)(1024 + b) * L_ + j] = mask[b * L_ + j] ? 0x3F80 : 0;
            }
        }
        return;
    }
    const float* in; unsigned short* outp; int R, C; const int* mrow = nullptr; size_t bo = 0;
    int bx, by;
    if (r < 2048) {
        int z = r >> 9, rem = r & 511; by = rem >> 3; bx = rem & 7;
        in = x; outp = XmT; R = L_; C = 256; bo = (size_t)z * R * C; mrow = mask + z * L_;
    } else if (r < 2304) {
        int rem = r - 2048; bx = rem & 31; by = rem >> 5;
        in = W1; outp = W1T; R = 256; C = 1024;
    } else {
        int rem = r - 2304; bx = rem & 7; by = rem >> 3;
        in = W2; outp = W2T; R = 1024; C = 256;
    }
    int r0 = by * 32, c0 = bx * 32;
    int tx = t & 31, ty = t >> 5;
#pragma unroll
    for (int rr = 0; rr < 4; rr++) {
        int rw = ty + rr * 8;
        tile[rw][tx] = in[bo + (size_t)(r0 + rw) * C + c0 + tx];
    }
    float mfac = 1.f;
    if (mrow) mfac = mrow[r0 + tx] ? 1.f : 0.f;
    __syncthreads();
#pragma unroll
    for (int rr = 0; rr < 4; rr++) {
        int c = ty + rr * 8;
        outp[bo + (size_t)(c0 + c) * R + r0 + tx] = f2bf(tile[tx][c] * mfac);
    }
}

// ---------------- E = exp(sin^2(0.5*clip(m.mT))) via MFMA, bf16 out ----------------
__global__ __launch_bounds__(256) void k_scores_mfma(const unsigned short* __restrict__ mb,
                                                     unsigned short* __restrict__ E) {
    const int t = threadIdx.x, lane = t & 63, wid = t >> 6;
    const int wm = (wid >> 1) * 64, wn = (wid & 1) * 32;
    const int lr = lane & 15, lq = lane >> 4;
    int m0 = blockIdx.y * 128, n0 = blockIdx.x * 64;
    bf16x8 af[4], bfr[2];
#pragma unroll
    for (int i = 0; i < 4; i++)
        af[i] = *(const bf16x8*)(mb + (size_t)(m0 + wm + i * 16 + lr) * 32 + lq * 8);
#pragma unroll
    for (int j = 0; j < 2; j++)
        bfr[j] = *(const bf16x8*)(mb + (size_t)(n0 + wn + j * 16 + lr) * 32 + lq * 8);
    floatx4 acc[4][2];
#pragma unroll
    for (int i = 0; i < 4; i++)
#pragma unroll
        for (int j = 0; j < 2; j++) {
            acc[i][j] = (floatx4){0.f, 0.f, 0.f, 0.f};
            acc[i][j] = __builtin_amdgcn_mfma_f32_16x16x32_bf16(af[i], bfr[j], acc[i][j], 0, 0, 0);
        }
#pragma unroll
    for (int i = 0; i < 4; i++)
#pragma unroll
        for (int j = 0; j < 2; j++)
#pragma unroll
            for (int r = 0; r < 4; r++) {
                int row = m0 + wm + i * 16 + lq * 4 + r;
                int col = n0 + wn + j * 16 + lr;
                float d = fminf(fmaxf(acc[i][j][r], -PI_F), PI_F);
                float sn = __sinf(0.5f * d);
                E[(size_t)row * L_ + col] = f2bf(__expf(sn * sn));
            }
}

// ---------------- AV: C[2048,1088] = E @ XmT^T (bf16 out), 3-deep counted-vmcnt ----------------
__global__ __launch_bounds__(256) void k_av(const unsigned short* __restrict__ E,
                                            const unsigned short* __restrict__ XmT,
                                            unsigned short* __restrict__ Cb) {
    __shared__ __align__(16) unsigned short sbuf[3][128 * 64 + 64 * 64];
    const int t = threadIdx.x, lane = t & 63, wid = t >> 6;
    const int wm = (wid >> 1) * 64, wn = (wid & 1) * 32;
    const int lr = lane & 15, lq = lane >> 4;
    const int lrow = lane >> 3, lseg = lane & 7;

    int bid = blockIdx.x;
    int swz = (bid & 7) * 34 + (bid >> 3);
    int m0 = (swz / 17) * 128, n0 = (swz % 17) * 64;

    const unsigned short* Ag[4]; int sAoff[4];
#pragma unroll
    for (int q = 0; q < 4; q++) {
        int rl = wid * 32 + q * 8 + lrow;
        Ag[q] = E + (size_t)(m0 + rl) * L_ + ((lseg - rl) & 7) * 8;
        sAoff[q] = (wid * 32 + q * 8) * 64;
    }
    const unsigned short* Bg[2]; int sBoff[2];
#pragma unroll
    for (int q = 0; q < 2; q++) {
        int rl = wid * 16 + q * 8 + lrow;
        Bg[q] = XmT + (size_t)(n0 + rl) * L_ + ((lseg - rl) & 7) * 8;
        sBoff[q] = 8192 + (wid * 16 + q * 8) * 64;
    }
    int arot[4], aroff[4], brot[2], broff[2];
#pragma unroll
    for (int i = 0; i < 4; i++) { int ar = wm + i * 16 + lr; aroff[i] = ar * 64; arot[i] = lq + ar; }
#pragma unroll
    for (int j = 0; j < 2; j++) { int br = wn + j * 16 + lr; broff[j] = 8192 + br * 64; brot[j] = lq + br; }

    floatx4 acc[4][2];
#pragma unroll
    for (int i = 0; i < 4; i++)
#pragma unroll
        for (int j = 0; j < 2; j++) acc[i][j] = (floatx4){0.f, 0.f, 0.f, 0.f};

    auto stage = [&](unsigned short* base, int k0) {
#pragma unroll
        for (int q = 0; q < 4; q++) async_cp16(base + sAoff[q], Ag[q] + k0);
#pragma unroll
        for (int q = 0; q < 2; q++) async_cp16(base + sBoff[q], Bg[q] + k0);
    };
    auto compute = [&](const unsigned short* base) {
#pragma unroll
        for (int s = 0; s < 2; s++) {
            bf16x8 af[4], bfr[2];
#pragma unroll
            for (int i = 0; i < 4; i++)
                af[i] = *(const bf16x8*)(base + aroff[i] + ((s * 4 + arot[i]) & 7) * 8);
#pragma unroll
            for (int j = 0; j < 2; j++)
                bfr[j] = *(const bf16x8*)(base + broff[j] + ((s * 4 + brot[j]) & 7) * 8);
#pragma unroll
            for (int i = 0; i < 4; i++)
#pragma unroll
                for (int j = 0; j < 2; j++)
                    acc[i][j] = __builtin_amdgcn_mfma_f32_16x16x32_bf16(af[i], bfr[j], acc[i][j], 0, 0, 0);
        }
    };

    unsigned short *p0 = sbuf[0], *p1 = sbuf[1], *p2 = sbuf[2];
    stage(p0, 0); stage(p1, 64); stage(p2, 128);
    WAIT_VM(12); BARRIER();
    for (int p = 0; p < 29; ++p) {
        compute(p0);
        BARRIER();
        stage(p0, (p + 3) << 6);
        WAIT_VM(12); BARRIER();
        unsigned short* tmp = p0; p0 = p1; p1 = p2; p2 = tmp;
    }
    compute(p0);
    BARRIER();
    WAIT_VM(6); BARRIER();
    compute(p1);
    BARRIER();
    WAIT_VM(0); BARRIER();
    compute(p2);

#pragma unroll
    for (int i = 0; i < 4; i++)
#pragma unroll
        for (int j = 0; j < 2; j++)
#pragma unroll
            for (int r = 0; r < 4; r++) {
                int row = m0 + wm + i * 16 + lq * 4 + r;
                int col = n0 + wn + j * 16 + lr;
                Cb[(size_t)row * 1088 + col] = f2bf(acc[i][j][r]);
            }
}

// ---------------- k_ffn: out = LN2( h + relu(h@W1+b1)@W2 + b2 ),  h = LN1(x + C/rs)
//                  256 blocks x 32 tokens; h in LDS + A-frags in regs; t1 per-chunk LDS tile ----------------
__global__ __launch_bounds__(256, 1) void k_ffn(const float* __restrict__ x,
                                                const unsigned short* __restrict__ Cb,
                                                const unsigned short* __restrict__ W1T,
                                                const unsigned short* __restrict__ W2T,
                                                const float* __restrict__ b1,
                                                const float* __restrict__ b2,
                                                const float* __restrict__ g1, const float* __restrict__ be1,
                                                const float* __restrict__ g2, const float* __restrict__ be2,
                                                float* __restrict__ out) {
    __shared__ __align__(16) unsigned short hA[4 * 32 * 64];        // 16 KB: h, [kc][row][seg-rotated]
    __shared__ __align__(16) unsigned short W1b[2][4 * 64 * 64];    // 2 x 32 KB
    __shared__ __align__(16) unsigned short W2b[4 * 64 * 64];       // 32 KB: [nc=wid][n][seg-rotated]
    __shared__ __align__(16) unsigned short t1c[32 * 72];           // 4.5 KB row-major, pad 8
    __shared__ float red[4][32][2];

    const int t = threadIdx.x, lane = t & 63, wid = t >> 6;
    const int lr = lane & 15, lq = lane >> 4;
    const int half = lane >> 5, l32 = lane & 31;
    const int m0 = blockIdx.x * 32;

    // ---- per-lane global preloads (keep main loop free of non-stage vmem) ----
    float b1v[16];
#pragma unroll
    for (int c = 0; c < 16; c++) b1v[c] = b1[c * 64 + wid * 16 + lr];
    float4 g1a = *(const float4*)(g1 + l32 * 8);
    float4 g1b = *(const float4*)(g1 + l32 * 8 + 4);
    float4 be1a = *(const float4*)(be1 + l32 * 8);
    float4 be1b = *(const float4*)(be1 + l32 * 8 + 4);
    WAIT_VM(0);

    // ---- issue weight prefetch (lands during LN1 phase) ----
    // W1 chunk layout: [kc 0..3][fl 0..63][seg rotated by fl], granule=8 elems
    auto stageW1 = [&](unsigned short* buf, int fc) {
#pragma unroll
        for (int q = 0; q < 8; q++) {
            int kc = q >> 1, sub = q & 1;
            int fl = sub * 32 + wid * 8 + (lane >> 3);
            int kk = lane & 7;
            const unsigned short* src = W1T + (size_t)(fc * 64 + fl) * 256 + kc * 64 + (((kk - fl) & 7) * 8);
            async_cp16(W1b[0] + (buf - W1b[0]) + kc * 4096 + sub * 2048 + wid * 512, src);
        }
    };
    auto stageW2 = [&](int fc) {
#pragma unroll
        for (int q = 0; q < 8; q++) {
            int nc = q >> 1, sub = q & 1;
            int nl = sub * 32 + wid * 8 + (lane >> 3);
            int kk = lane & 7;
            const unsigned short* src = W2T + (size_t)(nc * 64 + nl) * 1024 + fc * 64 + (((kk - nl) & 7) * 8);
            async_cp16(W2b + nc * 4096 + sub * 2048 + wid * 512, src);
        }
    };
    stageW1(W1b[0], 0);
    stageW2(0);
    stageW1(W1b[1], 1);

    // ---- LN1 phase: h[32][256] -> hA (rotate-swizzled), 2 tokens/wave/iter ----
#pragma unroll
    for (int it = 0; it < 4; it++) {
        int tloc = wid * 8 + it * 2 + half;
        int tok = m0 + tloc;
        int bi = tok >> 11, ii = tok & (L_ - 1);
        float rs = bf2f(Cb[(size_t)ii * 1088 + 1024 + bi]);
        float4 xv0 = *(const float4*)(x + (size_t)tok * D_ + l32 * 8);
        float4 xv1 = *(const float4*)(x + (size_t)tok * D_ + l32 * 8 + 4);
        ushortx8 cv = *(const ushortx8*)(Cb + (size_t)ii * 1088 + bi * 256 + l32 * 8);
        float v[8];
        v[0] = xv0.x + bf2f(cv[0]) / rs; v[1] = xv0.y + bf2f(cv[1]) / rs;
        v[2] = xv0.z + bf2f(cv[2]) / rs; v[3] = xv0.w + bf2f(cv[3]) / rs;
        v[4] = xv1.x + bf2f(cv[4]) / rs; v[5] = xv1.y + bf2f(cv[5]) / rs;
        v[6] = xv1.z + bf2f(cv[6]) / rs; v[7] = xv1.w + bf2f(cv[7]) / rs;
        float s = 0.f, s2 = 0.f;
#pragma unroll
        for (int k = 0; k < 8; k++) { s += v[k]; s2 += v[k] * v[k]; }
#pragma unroll
        for (int o = 1; o < 32; o <<= 1) { s += __shfl_xor(s, o); s2 += __shfl_xor(s2, o); }
        float mu = s * (1.f / 256.f);
        float var = s2 * (1.f / 256.f) - mu * mu;
        float rq = rsqrtf(var + 1e-5f);
        union { bf16x8 v8; unsigned short u[8]; } hv;
        hv.u[0] = f2bf((v[0] - mu) * rq * g1a.x + be1a.x);
        hv.u[1] = f2bf((v[1] - mu) * rq * g1a.y + be1a.y);
        hv.u[2] = f2bf((v[2] - mu) * rq * g1a.z + be1a.z);
        hv.u[3] = f2bf((v[3] - mu) * rq * g1a.w + be1a.w);
        hv.u[4] = f2bf((v[4] - mu) * rq * g1b.x + be1b.x);
        hv.u[5] = f2bf((v[5] - mu) * rq * g1b.y + be1b.y);
        hv.u[6] = f2bf((v[6] - mu) * rq * g1b.z + be1b.z);
        hv.u[7] = f2bf((v[7] - mu) * rq * g1b.w + be1b.w);
        *(bf16x8*)(hA + (l32 >> 3) * 2048 + tloc * 64 + ((((l32 & 7) + tloc) & 7) * 8)) = hv.v8;
    }
    WAIT_LGKM(); BARRIER();

    // ---- hoist h A-fragments to registers: haf[i][kc*2+s] ----
    bf16x8 haf[2][8];
#pragma unroll
    for (int i = 0; i < 2; i++)
#pragma unroll
        for (int kc = 0; kc < 4; kc++)
#pragma unroll
            for (int s = 0; s < 2; s++) {
                int row = i * 16 + lr;
                haf[i][kc * 2 + s] = *(const bf16x8*)(hA + kc * 2048 + row * 64 + (((s * 4 + lq + row) & 7) * 8));
            }

    floatx4 acc[2][4];
#pragma unroll
    for (int i = 0; i < 2; i++)
#pragma unroll
        for (int j = 0; j < 4; j++) acc[i][j] = (floatx4){0.f, 0.f, 0.f, 0.f};

    const int wcol = wid * 16 + lr;          // GEMM1 output col (local f)
    // chunk body as macro-lambda; c compile-time via unroll
    auto gemm1 = [&](const unsigned short* wb, floatx4 a1[2]) {
#pragma unroll
        for (int kc = 0; kc < 4; kc++)
#pragma unroll
            for (int s = 0; s < 2; s++) {
                bf16x8 bfr = *(const bf16x8*)(wb + kc * 4096 + wcol * 64 + (((s * 4 + lq + wcol) & 7) * 8));
                a1[0] = __builtin_amdgcn_mfma_f32_16x16x32_bf16(haf[0][kc * 2 + s], bfr, a1[0], 0, 0, 0);
                a1[1] = __builtin_amdgcn_mfma_f32_16x16x32_bf16(haf[1][kc * 2 + s], bfr, a1[1], 0, 0, 0);
            }
    };
    auto t1write = [&](floatx4 a1[2], float bv) {
#pragma unroll
        for (int i = 0; i < 2; i++)
#pragma unroll
            for (int r = 0; r < 4; r++)
                t1c[(i * 16 + lq * 4 + r) * 72 + wcol] = f2bf(fmaxf(a1[i][r] + bv, 0.f));
    };
    auto gemm2 = [&]() {
#pragma unroll
        for (int s = 0; s < 2; s++) {
            bf16x8 af0 = *(const bf16x8*)(t1c + lr * 72 + s * 32 + lq * 8);
            bf16x8 af1 = *(const bf16x8*)(t1c + (16 + lr) * 72 + s * 32 + lq * 8);
#pragma unroll
            for (int j = 0; j < 4; j++) {
                int nl = j * 16 + lr;
                bf16x8 bfr = *(const bf16x8*)(W2b + wid * 4096 + nl * 64 + (((s * 4 + lq + nl) & 7) * 8));
                acc[0][j] = __builtin_amdgcn_mfma_f32_16x16x32_bf16(af0, bfr, acc[0][j], 0, 0, 0);
                acc[1][j] = __builtin_amdgcn_mfma_f32_16x16x32_bf16(af1, bfr, acc[1][j], 0, 0, 0);
            }
        }
    };

    // ---- main loop: chunks 0..13 (uniform), 14,15 peeled ----
#pragma unroll
    for (int c = 0; c < 14; c++) {
        floatx4 a1[2] = { (floatx4){0.f,0.f,0.f,0.f}, (floatx4){0.f,0.f,0.f,0.f} };
        gemm1(W1b[c & 1], a1);
        BARRIER();                            // done reading W1b[c&1]
        stageW1(W1b[c & 1], c + 2);           // 8 issues
        t1write(a1, b1v[c]);
        WAIT_LGKM();
        WAIT_VM(8); BARRIER();                // W2(c) landed (keep W1(c+2)); t1c visible
        gemm2();
        BARRIER();                            // done reading W2b + t1c
        stageW2(c + 1);                       // 8 issues
    }
    {   // c = 14
        floatx4 a1[2] = { (floatx4){0.f,0.f,0.f,0.f}, (floatx4){0.f,0.f,0.f,0.f} };
        gemm1(W1b[0], a1);
        BARRIER();
        t1write(a1, b1v[14]);
        WAIT_LGKM();
        WAIT_VM(0); BARRIER();                // W2(14) landed (drains W1(15) early too)
        gemm2();
        BARRIER();
        stageW2(15);
    }
    {   // c = 15
        floatx4 a1[2] = { (floatx4){0.f,0.f,0.f,0.f}, (floatx4){0.f,0.f,0.f,0.f} };
        gemm1(W1b[1], a1);
        BARRIER();
        t1write(a1, b1v[15]);
        WAIT_LGKM();
        WAIT_VM(0); BARRIER();                // W2(15) landed
        gemm2();
    }

    // ---- LN2 epilogue (residual h from hA) ----
    float psum[2][4], psq[2][4];
#pragma unroll
    for (int i = 0; i < 2; i++)
#pragma unroll
        for (int r = 0; r < 4; r++) { psum[i][r] = 0.f; psq[i][r] = 0.f; }
#pragma unroll
    for (int i = 0; i < 2; i++)
#pragma unroll
        for (int j = 0; j < 4; j++) {
            int col = wid * 64 + j * 16 + lr;
            float bv = b2[col];
            int kc = col >> 6, ks = (col >> 3) & 7, ke = col & 7;
#pragma unroll
            for (int r = 0; r < 4; r++) {
                int row = i * 16 + lq * 4 + r;
                float hres = bf2f(hA[kc * 2048 + row * 64 + (((ks + row) & 7) * 8) + ke]);
                float v = acc[i][j][r] + bv + hres;
                acc[i][j][r] = v;
                psum[i][r] += v; psq[i][r] += v * v;
            }
        }
#pragma unroll
    for (int o = 1; o < 16; o <<= 1)
#pragma unroll
        for (int i = 0; i < 2; i++)
#pragma unroll
            for (int r = 0; r < 4; r++) { psum[i][r] += __shfl_xor(psum[i][r], o); psq[i][r] += __shfl_xor(psq[i][r], o); }
    if (lr == 0) {
#pragma unroll
        for (int i = 0; i < 2; i++)
#pragma unroll
            for (int r = 0; r < 4; r++) {
                int lrow = i * 16 + lq * 4 + r;
                red[wid][lrow][0] = psum[i][r];
                red[wid][lrow][1] = psq[i][r];
            }
    }
    __syncthreads();
#pragma unroll
    for (int i = 0; i < 2; i++)
#pragma unroll
        for (int r = 0; r < 4; r++) {
            int lrow = i * 16 + lq * 4 + r;
            float s  = red[0][lrow][0] + red[1][lrow][0] + red[2][lrow][0] + red[3][lrow][0];
            float s2 = red[0][lrow][1] + red[1][lrow][1] + red[2][lrow][1] + red[3][lrow][1];
            float mu = s * (1.f / 256.f);
            float var = s2 * (1.f / 256.f) - mu * mu;
            float rc = rsqrtf(var + 1e-5f);
            int row = m0 + lrow;
#pragma unroll
            for (int j = 0; j < 4; j++) {
                int col = wid * 64 + j * 16 + lr;
                out[(size_t)row * 256 + col] = (acc[i][j][r] - mu) * rc * g2[col] + be2[col];
            }
        }
}

extern "C" void kernel_launch(void* const* d_in, const int* in_sizes, int n_in,
                              void* d_out, int out_size, void* d_ws, size_t ws_size,
                              hipStream_t stream) {
    const float* x   = (const float*)d_in[0];
    const int*  mask = (const int*)d_in[1];
    const float* W1  = (const float*)d_in[2];
    const float* b1  = (const float*)d_in[3];
    const float* W2  = (const float*)d_in[4];
    const float* b2  = (const float*)d_in[5];
    const float* g1  = (const float*)d_in[6];
    const float* be1 = (const float*)d_in[7];
    const float* g2  = (const float*)d_in[8];
    const float* be2 = (const float*)d_in[9];
    float* out = (float*)d_out;

    char* w = (char*)d_ws;
    unsigned short* mb_   = (unsigned short*)w;  w += 65536 * 2;                 // 128 KB
    unsigned short* E_    = (unsigned short*)w;  w += (size_t)L_ * L_ * 2;       // 8 MB
    unsigned short* XmT_  = (unsigned short*)w;  w += (size_t)1088 * L_ * 2;     // 4.25 MB
    unsigned short* W1T_  = (unsigned short*)w;  w += 262144 * 2;                // 512 KB
    unsigned short* W2T_  = (unsigned short*)w;  w += 262144 * 2;                // 512 KB
    unsigned short* Cb_   = (unsigned short*)w;  w += (size_t)L_ * 1088 * 2;     // 4.25 MB

    k_prep<<<2817, 256, 0, stream>>>(x, W1, W2, mask, mb_, XmT_, W1T_, W2T_);
    k_scores_mfma<<<dim3(32, 16), 256, 0, stream>>>(mb_, E_);
    k_av<<<272, 256, 0, stream>>>(E_, XmT_, Cb_);
    k_ffn<<<256, 256, 0, stream>>>(x, Cb_, W1T_, W2T_, b1, b2, g1, be1, g2, be2, out);
}